// Round 1
// baseline (665.972 us; speedup 1.0000x reference)
//
#include <hip/hip_runtime.h>
#include <hip/hip_fp16.h>

#define B_ 256
#define T_ 200
#define H_ 256
#define G3 768            // 3*H
#define NV 50001          // V+1
#define KP 128            // K/2 half2 pairs (pack offset constant)
#define NU 1536           // units = 768 cols x 2 K-halves
#define PP 64             // half2 pairs per unit (128 K each)

using half2v = __attribute__((ext_vector_type(2))) _Float16;

union U32H2 { unsigned int u; half2v h; };

__device__ __forceinline__ float fdot2(half2v a, half2v b, float c) {
  return __builtin_amdgcn_fdot2(a, b, c, false);
}
__device__ __forceinline__ float sigmoidf_(float x) {
  return 1.f / (1.f + __expf(-x));
}
__device__ __forceinline__ float tanhf_(float x) {
  float ax = fabsf(x);
  float e = __expf(-2.f * ax);
  float t = (1.f - e) / (1.f + e);
  return copysignf(t, x);
}

// Pre-pack: w (fp32 [256 x 768]) -> unit-major K-pair-packed fp16.
// Unit u in [0,1536): u = kh*768 + col (kh = K-half). Pair p in [0,64):
// out[m*98304 + p*1536 + u] = (w[kh*128+2p][col], w[kh*128+2p+1][col]).
// Thread t of the compute kernels owns units {t, 512+t, 1024+t} -> its
// loads wp[p*1536 + j*512 + t] are coalesced across t.
__global__ __launch_bounds__(256) void pack_w2(
    const float* __restrict__ wih, const float* __restrict__ whh,
    unsigned int* __restrict__ out) {
  int idx = blockIdx.x * 256 + threadIdx.x;  // 0 .. 2*98304-1
  int m = idx / (PP * NU);
  int r = idx - m * (PP * NU);
  int p = r / NU;
  int u = r - p * NU;
  int kh = u / G3;
  int col = u - kh * G3;
  int k = kh * 128 + 2 * p;
  const float* w = m ? whh : wih;
  U32H2 v;
  v.h.x = (_Float16)w[(size_t)k * G3 + col];
  v.h.y = (_Float16)w[(size_t)(k + 1) * G3 + col];
  out[idx] = v.u;
}

// Load this thread's 3 units (192 VGPRs of weights).
__device__ __forceinline__ void load_w3(const unsigned int* __restrict__ wp,
                                        int t, half2v W[3][PP]) {
#pragma unroll
  for (int j = 0; j < 3; ++j)
#pragma unroll
    for (int p = 0; p < PP; ++p) {
      U32H2 u;
      u.u = wp[(size_t)p * NU + j * 512 + t];
      W[j][p] = u.h;
    }
}

// 3 partial dots (one per unit) against the packed fp16 vector in LDS.
// h2 = 128 uints (256 halfs). Unit j=0 uses K-half 0, j=2 uses K-half 1,
// j=1 uses half (t>=256) -> h1 = 0 or 64 uints (wave-uniform).
__device__ __forceinline__ void dot3(const half2v W[3][PP],
                                     const unsigned int* __restrict__ h2,
                                     int h1, float& r0, float& r1, float& r2) {
  const uint4* b0 = (const uint4*)(h2);
  const uint4* b1 = (const uint4*)(h2 + h1);
  const uint4* b2 = (const uint4*)(h2 + 64);
  float a00 = 0.f, a01 = 0.f, a10 = 0.f, a11 = 0.f, a20 = 0.f, a21 = 0.f;
#pragma unroll
  for (int i = 0; i < PP / 4; ++i) {
    uint4 v0 = b0[i];
    uint4 v1 = b1[i];
    uint4 v2 = b2[i];
    U32H2 c;
    c.u = v0.x; a00 = fdot2(W[0][4 * i + 0], c.h, a00);
    c.u = v1.x; a10 = fdot2(W[1][4 * i + 0], c.h, a10);
    c.u = v2.x; a20 = fdot2(W[2][4 * i + 0], c.h, a20);
    c.u = v0.y; a01 = fdot2(W[0][4 * i + 1], c.h, a01);
    c.u = v1.y; a11 = fdot2(W[1][4 * i + 1], c.h, a11);
    c.u = v2.y; a21 = fdot2(W[2][4 * i + 1], c.h, a21);
    c.u = v0.z; a00 = fdot2(W[0][4 * i + 2], c.h, a00);
    c.u = v1.z; a10 = fdot2(W[1][4 * i + 2], c.h, a10);
    c.u = v2.z; a20 = fdot2(W[2][4 * i + 2], c.h, a20);
    c.u = v0.w; a01 = fdot2(W[0][4 * i + 3], c.h, a01);
    c.u = v1.w; a11 = fdot2(W[1][4 * i + 3], c.h, a11);
    c.u = v2.w; a21 = fdot2(W[2][4 * i + 3], c.h, a21);
  }
  r0 = a00 + a01;
  r1 = a10 + a11;
  r2 = a20 + a21;
}

// K1: gates_x[b,t,col] = emb[ids[b,t]] . w_ih[:,col] + b_ih[col], fp16 out.
// wg g at iteration m handles (b=(g+m)&255, t=m): balanced, no atomics.
// 512 threads, 2 waves/SIMD -> 256-VGPR budget, weights register-resident.
__global__ __launch_bounds__(512, 2) void gates_kernel(
    const int* __restrict__ ids, const int* __restrict__ lens,
    const float* __restrict__ emb, const unsigned int* __restrict__ wih_p,
    const float* __restrict__ b_ih, __half* __restrict__ gates) {
  __shared__ __half xpk[2][256];
  __shared__ float part[NU];
  __shared__ int len_s[256];
  const int tid = threadIdx.x;
  const int g = blockIdx.x;
  const int h1 = (tid >= 256) ? 64 : 0;

  half2v W[3][PP];
  load_w3(wih_p, tid, W);
  const float bi_a = b_ih[tid];
  const float bi_b = (tid < 256) ? b_ih[512 + tid] : 0.f;

  if (tid < 256) {
    len_s[tid] = lens[tid];
    int id0 = ids[(size_t)g * T_];
    xpk[0][tid] = (__half)emb[(size_t)id0 * H_ + tid];
  }
  __syncthreads();

  int idNext = ids[(size_t)((g + 1) & 255) * T_ + 1];
  for (int m = 0; m < T_; ++m) {
    const int b = (g + m) & 255;
    const bool valid = (m < len_s[b]);
    const int bn = (g + m + 1) & 255;
    const bool validN = (m + 1 < T_) && ((m + 1) < len_s[bn]);
    const int cur = m & 1, nxt = cur ^ 1;

    float xv = 0.f;
    if (tid < 256 && validN) xv = emb[(size_t)idNext * H_ + tid];
    int idN2 = (m + 2 < T_) ? ids[(size_t)((g + m + 2) & 255) * T_ + (m + 2)] : 0;

    if (valid) {
      float r0, r1, r2;
      dot3(W, (const unsigned int*)&xpk[cur][0], h1, r0, r1, r2);
      part[tid] = r0;
      part[512 + tid] = r1;
      part[1024 + tid] = r2;
    }
    __syncthreads();
    if (valid) {
      __half* gp = gates + ((size_t)b * T_ + m) * G3;
      gp[tid] = (__half)(part[tid] + part[768 + tid] + bi_a);
      if (tid < 256)
        gp[512 + tid] = (__half)(part[512 + tid] + part[1280 + tid] + bi_b);
    }
    if (tid < 256 && validN) xpk[nxt][tid] = (__half)xv;
    idNext = idN2;
    __syncthreads();
  }
}

// K2: sequential GRU recurrence, one wg per batch row, w_hh register-resident
// (192 VGPRs/thread across 8 waves = 393 KB of the 512 KB/CU file).
__global__ __launch_bounds__(512, 2) void rec_kernel(
    const int* __restrict__ lens, const unsigned int* __restrict__ whh_p,
    const float* __restrict__ b_hh, const __half* __restrict__ gates,
    float* __restrict__ hfin) {
  __shared__ float part[NU];
  __shared__ __half hpk[256];
  const int tid = threadIdx.x;
  const int b = blockIdx.x;
  const int h1 = (tid >= 256) ? 64 : 0;

  half2v W[3][PP];
  load_w3(whh_p, tid, W);

  const int len = lens[b];
  float bh0 = 0.f, bh1 = 0.f, bh2 = 0.f;
  float h = 0.f;
  if (tid < 256) {
    bh0 = b_hh[tid];
    bh1 = b_hh[256 + tid];
    bh2 = b_hh[512 + tid];
    hpk[tid] = (__half)0.f;
  }
  __syncthreads();

  const __half* gp = gates + (size_t)b * T_ * G3 + tid;
  for (int t = 0; t < len; ++t) {
    float gxz = 0.f, gxr = 0.f, gxh = 0.f;
    if (tid < 256) {  // prefetch; consumed after the barrier
      const __half* gpt = gp + (size_t)t * G3;
      gxz = (float)gpt[0];
      gxr = (float)gpt[256];
      gxh = (float)gpt[512];
    }
    float r0, r1, r2;
    dot3(W, (const unsigned int*)&hpk[0], h1, r0, r1, r2);
    part[tid] = r0;
    part[512 + tid] = r1;
    part[1024 + tid] = r2;
    __syncthreads();
    if (tid < 256) {
      float z = sigmoidf_(gxz + part[tid] + part[768 + tid] + bh0);
      float r = sigmoidf_(gxr + part[256 + tid] + part[1024 + tid] + bh1);
      float hh = tanhf_(gxh + r * (part[512 + tid] + part[1280 + tid] + bh2));
      h = z * h + (1.f - z) * hh;
      hpk[tid] = (__half)h;
    }
    __syncthreads();
  }
  if (tid < 256) hfin[(size_t)b * H_ + tid] = h;
}

// K3: logits[256 x 50001] = hfin @ emb^T, fp32 tiled GEMM (unchanged).
__global__ __launch_bounds__(256) void logits_kernel(
    const float* __restrict__ hfin, const float* __restrict__ emb,
    float* __restrict__ out) {
  __shared__ float hsT[32][64];
  __shared__ float esT[32][132];
  const int tid = threadIdx.x;
  const int tx = tid & 15, ty = tid >> 4;
  const int n0 = blockIdx.x * 128;
  const int b0 = blockIdx.y * 64;
  float acc[4][8];
#pragma unroll
  for (int i = 0; i < 4; ++i)
#pragma unroll
    for (int q = 0; q < 8; ++q) acc[i][q] = 0.f;

  for (int k0 = 0; k0 < H_; k0 += 32) {
    {
      int i = tid * 8;
      int r = i >> 5;
      int c = i & 31;
      const float* src = hfin + (size_t)(b0 + r) * H_ + k0 + c;
      float4 a0 = *(const float4*)(src);
      float4 a1 = *(const float4*)(src + 4);
      hsT[c + 0][r] = a0.x; hsT[c + 1][r] = a0.y;
      hsT[c + 2][r] = a0.z; hsT[c + 3][r] = a0.w;
      hsT[c + 4][r] = a1.x; hsT[c + 5][r] = a1.y;
      hsT[c + 6][r] = a1.z; hsT[c + 7][r] = a1.w;
    }
    {
      int r = tid >> 1;
      int c = (tid & 1) * 16;
      int n = n0 + r;
      float4 e0 = {0,0,0,0}, e1 = {0,0,0,0}, e2 = {0,0,0,0}, e3 = {0,0,0,0};
      if (n < NV) {
        const float* src = emb + (size_t)n * H_ + k0 + c;
        e0 = *(const float4*)(src);
        e1 = *(const float4*)(src + 4);
        e2 = *(const float4*)(src + 8);
        e3 = *(const float4*)(src + 12);
      }
      esT[c + 0][r] = e0.x;  esT[c + 1][r] = e0.y;
      esT[c + 2][r] = e0.z;  esT[c + 3][r] = e0.w;
      esT[c + 4][r] = e1.x;  esT[c + 5][r] = e1.y;
      esT[c + 6][r] = e1.z;  esT[c + 7][r] = e1.w;
      esT[c + 8][r] = e2.x;  esT[c + 9][r] = e2.y;
      esT[c + 10][r] = e2.z; esT[c + 11][r] = e2.w;
      esT[c + 12][r] = e3.x; esT[c + 13][r] = e3.y;
      esT[c + 14][r] = e3.z; esT[c + 15][r] = e3.w;
    }
    __syncthreads();
#pragma unroll
    for (int kk = 0; kk < 32; ++kk) {
      float4 hv = *(const float4*)&hsT[kk][ty * 4];
      float4 ea = *(const float4*)&esT[kk][tx * 8];
      float4 eb = *(const float4*)&esT[kk][tx * 8 + 4];
#define ROWFMA(i, hc)                                                     \
  acc[i][0] += hc * ea.x; acc[i][1] += hc * ea.y;                         \
  acc[i][2] += hc * ea.z; acc[i][3] += hc * ea.w;                         \
  acc[i][4] += hc * eb.x; acc[i][5] += hc * eb.y;                         \
  acc[i][6] += hc * eb.z; acc[i][7] += hc * eb.w;
      ROWFMA(0, hv.x)
      ROWFMA(1, hv.y)
      ROWFMA(2, hv.z)
      ROWFMA(3, hv.w)
#undef ROWFMA
    }
    __syncthreads();
  }
#pragma unroll
  for (int i = 0; i < 4; ++i) {
    int bb = b0 + ty * 4 + i;
    float* op = out + (size_t)bb * NV + n0 + tx * 8;
#pragma unroll
    for (int q = 0; q < 8; ++q) {
      int n = n0 + tx * 8 + q;
      if (n < NV) op[q] = acc[i][q];
    }
  }
}

extern "C" void kernel_launch(void* const* d_in, const int* in_sizes, int n_in,
                              void* d_out, int out_size, void* d_ws, size_t ws_size,
                              hipStream_t stream) {
  const int* ids = (const int*)d_in[0];
  const int* lens = (const int*)d_in[1];
  const float* emb = (const float*)d_in[2];
  const float* w_ih = (const float*)d_in[3];
  const float* w_hh = (const float*)d_in[4];
  const float* b_ih = (const float*)d_in[5];
  const float* b_hh = (const float*)d_in[6];
  float* out = (float*)d_out;

  char* ws = (char*)d_ws;
  __half* gates = (__half*)ws;                                   // 78.6 MB
  float* hfin = (float*)(ws + (size_t)B_ * T_ * G3 * sizeof(__half));
  unsigned int* wpack = (unsigned int*)(ws + (size_t)B_ * T_ * G3 * sizeof(__half)
                                        + (size_t)B_ * H_ * sizeof(float));
  unsigned int* wih_p = wpack;                                   // 393 KB
  unsigned int* whh_p = wpack + (size_t)KP * G3;                 // 393 KB

  pack_w2<<<dim3(2 * PP * NU / 256), dim3(256), 0, stream>>>(w_ih, w_hh, wpack);
  gates_kernel<<<dim3(B_), dim3(512), 0, stream>>>(ids, lens, emb, wih_p, b_ih, gates);
  rec_kernel<<<dim3(B_), dim3(512), 0, stream>>>(lens, whh_p, b_hh, gates, hfin);
  logits_kernel<<<dim3((NV + 127) / 128, B_ / 64), dim3(256), 0, stream>>>(hfin, emb, out);
}

// Round 2
// 438.611 us; speedup vs baseline: 1.5184x; 1.5184x over previous
//
#include <hip/hip_runtime.h>
#include <hip/hip_fp16.h>

#define B_ 256
#define T_ 200
#define H_ 256
#define G3 768            // 3*H
#define NV 50001          // V+1
#define KP 128            // K/2 half2 pairs for rec weight packing

typedef _Float16 half2v __attribute__((ext_vector_type(2)));
typedef _Float16 half4v __attribute__((ext_vector_type(4)));
typedef _Float16 half8v __attribute__((ext_vector_type(8)));
typedef float f32x4 __attribute__((ext_vector_type(4)));

union U32H2 { unsigned int u; half2v h; };

__device__ __forceinline__ float fdot2(half2v a, half2v b, float c) {
  return __builtin_amdgcn_fdot2(a, b, c, false);
}
__device__ __forceinline__ float sigmoidf_(float x) {
  return 1.f / (1.f + __expf(-x));
}
__device__ __forceinline__ float tanhf_(float x) {
  float ax = fabsf(x);
  float e = __expf(-2.f * ax);
  float t = (1.f - e) / (1.f + e);
  return copysignf(t, x);
}
__device__ __forceinline__ f32x4 mfma16(half8v a, half8v b, f32x4 c) {
  return __builtin_amdgcn_mfma_f32_16x16x32_f16(a, b, c, 0, 0, 0);
}

// ---- pack w_hh -> K-pair-packed fp16 (rec_kernel format):
// out[p*768+col] = (w[2p][col], w[2p+1][col]), p in [0,128).
__global__ __launch_bounds__(256) void pack_whh(
    const float* __restrict__ whh, unsigned int* __restrict__ out) {
  int idx = blockIdx.x * 256 + threadIdx.x;     // 0..98303
  int p = idx / G3;
  int col = idx - p * G3;
  U32H2 u;
  u.h.x = (_Float16)whh[(size_t)(2 * p) * G3 + col];
  u.h.y = (_Float16)whh[(size_t)(2 * p + 1) * G3 + col];
  out[idx] = u.u;
}

// ---- pack w_ih -> transposed fp16 [768 cols][256 k] (MFMA B staging format).
// out uint idx covers halfs (2*idx, 2*idx+1): col = idx>>7, kk = (idx&127)*2.
__global__ __launch_bounds__(256) void pack_wiht(
    const float* __restrict__ wih, unsigned int* __restrict__ out) {
  int idx = blockIdx.x * 256 + threadIdx.x;     // 0..98303
  int col = idx >> 7;
  int kk = (idx & 127) * 2;
  U32H2 u;
  u.h.x = (_Float16)wih[(size_t)kk * G3 + col];
  u.h.y = (_Float16)wih[(size_t)(kk + 1) * G3 + col];
  out[idx] = u.u;
}

// ---- K1: gates = emb[ids] @ w_ih + b_ih via f16 MFMA.
// M=51200 (b*T+t rows), N=768, K=256. Tile: 128 rows x 256 cols per WG,
// K chunks of 64, single-buffered LDS (54KB -> 2 WG/CU).
// Waves 2(m)x4(n); wave tile 64x64 = 4x4 subtiles of 16x16.
__global__ __launch_bounds__(512) void gates_mfma(
    const int* __restrict__ ids, const float* __restrict__ emb,
    const __half* __restrict__ wih_t, const float* __restrict__ b_ih,
    __half* __restrict__ gates) {
  __shared__ __align__(16) _Float16 As[128 * 72];   // [row][k] stride 72
  __shared__ __align__(16) _Float16 Bs[256 * 72];   // [col][k] stride 72
  __shared__ int ids_s[128];
  __shared__ float bs[256];
  const int tid = threadIdx.x;
  const int r0 = blockIdx.x * 128;
  const int c0 = blockIdx.y * 256;
  const int w = tid >> 6, lane = tid & 63;
  const int wm = w >> 2, wn = w & 3;
  const int lr = lane & 15, lk = lane >> 4;

  if (tid < 128) ids_s[tid] = ids[r0 + tid];
  if (tid < 256) bs[tid] = b_ih[c0 + tid];
  __syncthreads();

  f32x4 acc[4][4];
#pragma unroll
  for (int i = 0; i < 4; ++i)
#pragma unroll
    for (int j = 0; j < 4; ++j) acc[i][j] = (f32x4){0.f, 0.f, 0.f, 0.f};

  for (int c = 0; c < 4; ++c) {
    const int kc = c * 64;
    // A: gather 128 emb rows x 64 k fp32 -> f16
#pragma unroll
    for (int r4 = 0; r4 < 4; ++r4) {
      int q = tid + r4 * 512;
      int row = q >> 4;
      int kk = (q & 15) * 4;
      const float4 v = *(const float4*)&emb[(size_t)ids_s[row] * H_ + kc + kk];
      half4v hv = {(_Float16)v.x, (_Float16)v.y, (_Float16)v.z, (_Float16)v.w};
      *(half4v*)&As[row * 72 + kk] = hv;
    }
    // B: 256 cols x 64 k from pre-transposed fp16 w_ih
#pragma unroll
    for (int r4 = 0; r4 < 4; ++r4) {
      int q = tid + r4 * 512;
      int col = q >> 3;
      int cc = q & 7;
      uint4 v = *(const uint4*)((const unsigned short*)wih_t +
                                (size_t)(c0 + col) * H_ + kc + cc * 8);
      *(uint4*)&Bs[col * 72 + cc * 8] = v;
    }
    __syncthreads();
#pragma unroll
    for (int ks = 0; ks < 2; ++ks) {
      half8v af[4], bf[4];
#pragma unroll
      for (int i = 0; i < 4; ++i)
        af[i] = *(const half8v*)&As[(wm * 64 + i * 16 + lr) * 72 + ks * 32 + lk * 8];
#pragma unroll
      for (int j = 0; j < 4; ++j)
        bf[j] = *(const half8v*)&Bs[(wn * 64 + j * 16 + lr) * 72 + ks * 32 + lk * 8];
#pragma unroll
      for (int i = 0; i < 4; ++i)
#pragma unroll
        for (int j = 0; j < 4; ++j)
          acc[i][j] = mfma16(af[i], bf[j], acc[i][j]);
    }
    __syncthreads();
  }
#pragma unroll
  for (int j = 0; j < 4; ++j) {
    const int col = c0 + wn * 64 + j * 16 + lr;
    const float bj = bs[wn * 64 + j * 16 + lr];
#pragma unroll
    for (int i = 0; i < 4; ++i) {
      const int row = r0 + wm * 64 + i * 16 + lk * 4;
#pragma unroll
      for (int r = 0; r < 4; ++r)
        gates[(size_t)(row + r) * G3 + col] = (__half)(acc[i][j][r] + bj);
    }
  }
}

// ---- rec weight loading / dot (round-0 measured-254us structure, verbatim).
__device__ __forceinline__ void load_w768(const unsigned int* __restrict__ wp,
                                          int col, half2v W[KP]) {
#pragma unroll
  for (int p = 0; p < KP; ++p) {
    U32H2 u;
    u.u = wp[(size_t)p * G3 + col];
    W[p] = u.h;
  }
}

__device__ __forceinline__ float dot768(const half2v (&W)[KP],
                                        const unsigned int* __restrict__ x) {
  float a0 = 0.f, a1 = 0.f;
#pragma unroll
  for (int p4 = 0; p4 < KP / 4; ++p4) {
    uint4 v = ((const uint4*)x)[p4];
    U32H2 c0, c1, c2, c3;
    c0.u = v.x; c1.u = v.y; c2.u = v.z; c3.u = v.w;
    a0 = fdot2(W[4 * p4 + 0], c0.h, a0);
    a1 = fdot2(W[4 * p4 + 1], c1.h, a1);
    a0 = fdot2(W[4 * p4 + 2], c2.h, a0);
    a1 = fdot2(W[4 * p4 + 3], c3.h, a1);
  }
  return a0 + a1;
}

// ---- K2: sequential GRU recurrence, one wg per batch row.
__global__ __launch_bounds__(768, 3) void rec_kernel(
    const int* __restrict__ lens, const unsigned int* __restrict__ whh_p,
    const float* __restrict__ b_hh, const __half* __restrict__ gates,
    float* __restrict__ hfin) {
  __shared__ float rec[G3];
  __shared__ __half hpk[256];
  const int tid = threadIdx.x;
  const int b = blockIdx.x;

  half2v W[KP];
  load_w768(whh_p, tid, W);

  const int len = lens[b];
  float bh0 = 0.f, bh1 = 0.f, bh2 = 0.f;
  float h = 0.f;
  if (tid < 256) {
    bh0 = b_hh[tid];
    bh1 = b_hh[256 + tid];
    bh2 = b_hh[512 + tid];
    hpk[tid] = (__half)0.f;
  }
  __syncthreads();

  const __half* gp = gates + (size_t)b * T_ * G3 + tid;
  for (int t = 0; t < len; ++t) {
    float gxz = 0.f, gxr = 0.f, gxh = 0.f;
    if (tid < 256) {  // prefetch; consumed after the barrier
      const __half* gpt = gp + (size_t)t * G3;
      gxz = (float)gpt[0];
      gxr = (float)gpt[256];
      gxh = (float)gpt[512];
    }
    float d = dot768(W, (const unsigned int*)&hpk[0]);
    rec[tid] = d;
    __syncthreads();
    if (tid < 256) {
      float z = sigmoidf_(gxz + rec[tid] + bh0);
      float r = sigmoidf_(gxr + rec[256 + tid] + bh1);
      float hh = tanhf_(gxh + r * (rec[512 + tid] + bh2));
      h = z * h + (1.f - z) * hh;
      hpk[tid] = (__half)h;
    }
    __syncthreads();
  }
  if (tid < 256) hfin[(size_t)b * H_ + tid] = h;
}

// ---- K3: logits = hfin @ emb^T via hi/lo-split f16 MFMA (fp32-class accuracy).
// M=256 (all rows per WG -> emb read exactly once), N-tile 64, K chunks of 32.
// Waves 4(m)x2(n); wave tile 64x32 = 4x2 subtiles. Residuals scaled by 1024
// to stay in f16 normal range; result = main + aux/1024.
__global__ __launch_bounds__(512) void logits_mfma(
    const float* __restrict__ hfin, const float* __restrict__ emb,
    float* __restrict__ out) {
  // layout per row: [kslot(4)][sel(2)][8 halfs] = 64 used + 8 pad = 72
  __shared__ __align__(16) _Float16 As[256 * 72];
  __shared__ __align__(16) _Float16 Bs[64 * 72];
  const int tid = threadIdx.x;
  const int n0 = blockIdx.x * 64;
  const int w = tid >> 6, lane = tid & 63;
  const int wm = w >> 1, wn = w & 1;
  const int lr = lane & 15, lk = lane >> 4;

  f32x4 a1[4][2], a2[4][2];
#pragma unroll
  for (int i = 0; i < 4; ++i)
#pragma unroll
    for (int j = 0; j < 2; ++j) {
      a1[i][j] = (f32x4){0.f, 0.f, 0.f, 0.f};
      a2[i][j] = (f32x4){0.f, 0.f, 0.f, 0.f};
    }

  for (int c = 0; c < 8; ++c) {
    const int kc = c * 32;
    // A: 256 rows x 32 k fp32 -> hi/lo f16
#pragma unroll
    for (int r4 = 0; r4 < 4; ++r4) {
      int q = tid + r4 * 512;
      int row = q >> 3;
      int kk = (q & 7) * 4;
      float4 v = *(const float4*)&hfin[(size_t)row * H_ + kc + kk];
      half4v hi = {(_Float16)v.x, (_Float16)v.y, (_Float16)v.z, (_Float16)v.w};
      half4v lo = {(_Float16)((v.x - (float)hi.x) * 1024.f),
                   (_Float16)((v.y - (float)hi.y) * 1024.f),
                   (_Float16)((v.z - (float)hi.z) * 1024.f),
                   (_Float16)((v.w - (float)hi.w) * 1024.f)};
      int base = row * 72 + (kk >> 3) * 16 + (kk & 7);
      *(half4v*)&As[base] = hi;
      *(half4v*)&As[base + 8] = lo;
    }
    // B: 64 cols (vocab rows) x 32 k fp32 -> hi/lo f16
    {
      int col = tid >> 3;
      int kk = (tid & 7) * 4;
      int n = n0 + col;
      float4 v = (n < NV) ? *(const float4*)&emb[(size_t)n * H_ + kc + kk]
                          : make_float4(0.f, 0.f, 0.f, 0.f);
      half4v hi = {(_Float16)v.x, (_Float16)v.y, (_Float16)v.z, (_Float16)v.w};
      half4v lo = {(_Float16)((v.x - (float)hi.x) * 1024.f),
                   (_Float16)((v.y - (float)hi.y) * 1024.f),
                   (_Float16)((v.z - (float)hi.z) * 1024.f),
                   (_Float16)((v.w - (float)hi.w) * 1024.f)};
      int base = col * 72 + (kk >> 3) * 16 + (kk & 7);
      *(half4v*)&Bs[base] = hi;
      *(half4v*)&Bs[base + 8] = lo;
    }
    __syncthreads();
    half8v ah[4], al[4];
#pragma unroll
    for (int i = 0; i < 4; ++i) {
      int base = (wm * 64 + i * 16 + lr) * 72 + lk * 16;
      ah[i] = *(const half8v*)&As[base];
      al[i] = *(const half8v*)&As[base + 8];
    }
#pragma unroll
    for (int j = 0; j < 2; ++j) {
      int base = (wn * 32 + j * 16 + lr) * 72 + lk * 16;
      half8v bh = *(const half8v*)&Bs[base];
      half8v bl = *(const half8v*)&Bs[base + 8];
#pragma unroll
      for (int i = 0; i < 4; ++i) {
        a1[i][j] = mfma16(ah[i], bh, a1[i][j]);
        a2[i][j] = mfma16(ah[i], bl, a2[i][j]);
        a2[i][j] = mfma16(al[i], bh, a2[i][j]);
      }
    }
    __syncthreads();
  }
#pragma unroll
  for (int j = 0; j < 2; ++j) {
    int n = n0 + wn * 32 + j * 16 + lr;
    if (n < NV) {
#pragma unroll
      for (int i = 0; i < 4; ++i) {
        int row = wm * 64 + i * 16 + lk * 4;
#pragma unroll
        for (int r = 0; r < 4; ++r)
          out[(size_t)(row + r) * NV + n] =
              a1[i][j][r] + a2[i][j][r] * (1.f / 1024.f);
      }
    }
  }
}

extern "C" void kernel_launch(void* const* d_in, const int* in_sizes, int n_in,
                              void* d_out, int out_size, void* d_ws, size_t ws_size,
                              hipStream_t stream) {
  const int* ids = (const int*)d_in[0];
  const int* lens = (const int*)d_in[1];
  const float* emb = (const float*)d_in[2];
  const float* w_ih = (const float*)d_in[3];
  const float* w_hh = (const float*)d_in[4];
  const float* b_ih = (const float*)d_in[5];
  const float* b_hh = (const float*)d_in[6];
  float* out = (float*)d_out;

  char* ws = (char*)d_ws;
  __half* gates = (__half*)ws;                           // 78,643,200 B
  float* hfin = (float*)(ws + (size_t)B_ * T_ * G3 * sizeof(__half));
  unsigned int* whh_p =
      (unsigned int*)(ws + (size_t)B_ * T_ * G3 * sizeof(__half)
                      + (size_t)B_ * H_ * sizeof(float));   // 393,216 B
  unsigned int* wih_t = whh_p + (size_t)KP * G3;            // 393,216 B

  pack_whh<<<dim3(384), dim3(256), 0, stream>>>(w_hh, whh_p);
  pack_wiht<<<dim3(384), dim3(256), 0, stream>>>(w_ih, wih_t);
  gates_mfma<<<dim3(400, 3), dim3(512), 0, stream>>>(
      ids, emb, (const __half*)wih_t, b_ih, gates);
  rec_kernel<<<dim3(B_), dim3(768), 0, stream>>>(lens, whh_p, b_hh, gates, hfin);
  logits_mfma<<<dim3((NV + 63) / 64), dim3(512), 0, stream>>>(hfin, emb, out);
}